// Round 13
// baseline (3756.486 us; speedup 1.0000x reference)
//
#include <hip/hip_runtime.h>
#include <hip/hip_bf16.h>

#define NB 8
#define NN 8192
#define NP 2048
#define NS 32
#define INV_P (1.0f/524288.0f)   // 1/(B*NPOINT*NSAMPLE), exact power of 2

typedef float v2f __attribute__((ext_vector_type(2)));

template<int CTRL>
__device__ __forceinline__ float fmax_dpp(float v) {
  // bound_ctrl=true: invalid-source lanes read 0; distances >= 0 so max(v,0)=v is safe
  const int x = __builtin_amdgcn_update_dpp(0, __float_as_int(v), CTRL, 0xF, 0xF, true);
  return fmaxf(v, __int_as_float(x));
}

// ws layout (bytes):
//  0   : stats, 512 slots x 16 floats = 32KB
//  1MB : F = W1[:,3:]@feat + b1   (8*8192*64 f32 = 16MB)
//  32MB: y1 bf16 (524288*64) = 67MB
//  112MB: y2 bf16 (524288*64) = 67MB

// ---------------------------------------------------------------- K1: FPS (blocks 0..7, 128 thr = 2 waves, 64 pts/thread in VGPRs;
//      2-wave barrier domain, 1 wave/SIMD uncontended) + F precompute (blocks 8..2055, 32 rows each)
__global__ __launch_bounds__(128)
void k_fps_pre(const float* __restrict__ xyz, const float* __restrict__ feat,
               const float* __restrict__ W1, const float* __restrict__ b1,
               float* __restrict__ F, float* __restrict__ outXyz, float* __restrict__ stats)
{
#pragma clang fp contract(off)
  __shared__ union U { float4 xyzw[NN]; float fx[32*64]; } sh;
  __shared__ unsigned long long cand[2][2];
  __shared__ float ctrs[3*NP];   // 24KB centroid stash; global copy in epilogue
  const int t = threadIdx.x;
  if (blockIdx.x < 8) {
    const int b = blockIdx.x;
    const float* xb = xyz + (size_t)b*NN*3;
    // 64 pts/thread entirely in registers (32 v2f per coord + dd)
    v2f px[32], py[32], pz[32], dd[32];
#pragma unroll
    for (int j = 0; j < 32; ++j) {
      const int i0 = t*64 + 2*j;
      const float x0 = xb[i0*3+0], y0 = xb[i0*3+1], z0 = xb[i0*3+2];
      const float x1 = xb[i0*3+3], y1 = xb[i0*3+4], z1 = xb[i0*3+5];
      px[j] = (v2f){x0,x1}; py[j] = (v2f){y0,y1}; pz[j] = (v2f){z0,z1};
      dd[j] = (v2f){1e10f,1e10f};
      sh.xyzw[i0]   = make_float4(x0,y0,z0,0.f);
      sh.xyzw[i0+1] = make_float4(x1,y1,z1,0.f);
    }
    __syncthreads();
    const int lane = t & 63, wv = t >> 6;   // wv in {0,1}
    float4 cf = sh.xyzw[0];
    for (int s = 0; s < NP; ++s) {
      if (t == 0) { ctrs[3*s] = cf.x; ctrs[3*s+1] = cf.y; ctrs[3*s+2] = cf.z; }  // LDS only
      const v2f cx = {cf.x,cf.x}, cy = {cf.y,cf.y}, cz = {cf.z,cf.z};
      float m = -1.f; int mi = 0;
#pragma unroll
      for (int j = 0; j < 32; ++j) {
        // EXACT reference rounding: (dx*dx + dy*dy) + dz*dz, no fma (contract off);
        // v_pk_* ops round identically per lane-half
        const v2f dx = px[j]-cx, dy = py[j]-cy, dz = pz[j]-cz;
        v2f d = dx*dx; d = d + dy*dy; d = d + dz*dz;
        const float n0 = fminf(dd[j].x, d.x);   // jnp.minimum
        const float n1 = fminf(dd[j].y, d.y);
        dd[j].x = n0; dd[j].y = n1;
        if (n0 > m) { m = n0; mi = 2*j;   }     // strict > => first occurrence (inline, off the tail path)
        if (n1 > m) { m = n1; mi = 2*j+1; }
      }
      // wave64 value-max via DPP chain -> lane 63 -> SGPR broadcast
      float r = m;
      r = fmax_dpp<0xB1>(r);   // quad_perm [1,0,3,2]
      r = fmax_dpp<0x4E>(r);   // quad_perm [2,3,0,1]
      r = fmax_dpp<0x141>(r);  // row_half_mirror
      r = fmax_dpp<0x140>(r);  // row_mirror
      r = fmax_dpp<0x142>(r);  // row_bcast15
      r = fmax_dpp<0x143>(r);  // row_bcast31
      const int wmb  = __builtin_amdgcn_readlane(__float_as_int(r), 63);
      const float wm = __int_as_float(wmb);
      const unsigned long long mk = __ballot(m == wm);
      const int ls  = __ffsll((long long)mk) - 1;            // first lane achieving wave max
      const int miw = __builtin_amdgcn_readlane(mi, ls);
      const unsigned idx = (unsigned)((wv*64 + ls)*64 + miw);  // thread-order == point-order
      if (lane == 0)
        cand[s&1][wv] = ((unsigned long long)(unsigned)wmb << 32)
                      | (unsigned long long)(0xFFFFFFFFu - idx);   // ties -> smaller idx wins
      __syncthreads();   // 2-wave rendezvous only
      const unsigned long long k0 = cand[s&1][0], k1 = cand[s&1][1];
      const unsigned long long best = k0 > k1 ? k0 : k1;
      const int far = (int)(0xFFFFFFFFu - (unsigned)(best & 0xFFFFFFFFull));
      cf = sh.xyzw[far];
    }
    // epilogue: one cooperative 24KB LDS -> global copy (coalesced)
    __syncthreads();
    for (int i = t; i < 3*NP; i += 128) outXyz[(size_t)b*NP*3 + i] = ctrs[i];
  } else {
    if (blockIdx.x == 8) {             // zero the stats table once per launch
      for (int i = t; i < 512*16; i += 128) stats[i] = 0.f;
    }
    const int blk = blockIdx.x - 8;    // 0..2047, 32 point-rows each
    const int base = blk * 32;
    const int b = base >> 13;
    const int n0 = base & (NN-1);
    {
      const int row = t >> 2, seg = t & 3;   // 32 rows, 4 segs of 16 floats
      const float* src = feat + ((size_t)(b*NN + n0 + row))*64 + seg*16;
#pragma unroll
      for (int k = 0; k < 4; ++k) {
        const float4 v = *(const float4*)(src + k*4);
        *(float4*)&sh.fx[row*64 + seg*16 + k*4] = v;
      }
    }
    __syncthreads();
    const int o = t & 63, wv = t >> 6;   // wv in {0,1}, 16 rows each
    float w[64];
#pragma unroll
    for (int c = 0; c < 64; ++c) w[c] = W1[o*67 + 3 + c];
    const float bb = b1[o];
    for (int r = wv*16; r < wv*16+16; ++r) {
      float acc = bb;
#pragma unroll
      for (int c4 = 0; c4 < 16; ++c4) {
        const float4 xq = *(const float4*)&sh.fx[r*64 + c4*4];
        acc = fmaf(w[c4*4+0], xq.x, acc);
        acc = fmaf(w[c4*4+1], xq.y, acc);
        acc = fmaf(w[c4*4+2], xq.z, acc);
        acc = fmaf(w[c4*4+3], xq.w, acc);
      }
      F[((size_t)(b*NN + n0 + r))*64 + o] = acc;
    }
  }
}

// ---------------------------------------------------------------- K2: ball query (f64 exact-geometry membership) + gather + conv1 -> y1(bf16) + stats1
__global__ __launch_bounds__(256)
void k_ball(const float* __restrict__ xyz, const float* __restrict__ newXyz,
            const float* __restrict__ F, const float* __restrict__ W1,
            __hip_bfloat16* __restrict__ y1, float* __restrict__ stats)
{
  __shared__ float xs[NN], ys[NN], zs[NN];
  __shared__ int sel[4][NS];
  const int t = threadIdx.x;
  const int b = blockIdx.x >> 5;
  const int chunk = blockIdx.x & 31;
  const float* xb = xyz + (size_t)b*NN*3;
  for (int i = t; i < NN; i += 256) {
    xs[i] = xb[i*3+0]; ys[i] = xb[i*3+1]; zs[i] = xb[i*3+2];
  }
  __syncthreads();
  const int lane = t & 63, wv = t >> 6;
  const float w0 = W1[lane*67+0], w1 = W1[lane*67+1], w2 = W1[lane*67+2];
  const double rr = 0.2*0.2;   // exact Python double radius*radius
  float ls = 0.f, lq = 0.f;
  for (int qi = 0; qi < 16; ++qi) {
    const int q  = chunk*64 + wv*16 + qi;
    const int gq = b*NP + q;
    const float cx = newXyz[(size_t)gq*3+0], cy = newXyz[(size_t)gq*3+1], cz = newXyz[(size_t)gq*3+2];
    const double cxd = (double)cx, cyd = (double)cy, czd = (double)cz;
    const double ssd = cxd*cxd + cyd*cyd + czd*czd;
    int have = 0;
    for (int c0 = 0; c0 < NN; c0 += 64) {
      const int i = c0 + lane;
      // true squared distance in f64 (inputs are exact f32): robust to every
      // f32 ordering the reference might have used (min boundary gap ~2e-7 >> 1e-16)
      const double x = (double)xs[i], y = (double)ys[i], z = (double)zs[i];
      const double dot = x*cxd + y*cyd + z*czd;
      const double pn2 = x*x + y*y + z*z;
      const double d = -2.0*dot + ssd + pn2;
      const bool ok = d <= rr;
      const unsigned long long mk = __ballot(ok);
      const int rank = __popcll(mk & ((1ull<<lane)-1ull));
      if (ok && have + rank < NS) sel[wv][have+rank] = i;
      have += (int)__popcll(mk);
      if (have >= NS) break;
    }
    if (have > NS) have = NS;
    const int first = sel[wv][0];
    if (lane >= have && lane < NS) sel[wv][lane] = first;  // pad tail with first index
    for (int j = 0; j < NS; ++j) {
      const int i = sel[wv][j];
      const float dxn = xs[i]-cx, dyn = ys[i]-cy, dzn = zs[i]-cz;
      const float f = F[((size_t)(b*NN+i))*64 + lane];
      float yv = fmaf(w0,dxn,f); yv = fmaf(w1,dyn,yv); yv = fmaf(w2,dzn,yv);
      y1[((size_t)gq*NS + j)*64 + lane] = __float2bfloat16(yv);
      ls += yv; lq = fmaf(yv,yv,lq);
    }
  }
  atomicAdd(&stats[(0 +lane)*16], ls);
  atomicAdd(&stats[(64+lane)*16], lq);
}

// ---------------------------------------------------------------- staging helper: bf16 tile -> bn+relu -> LDS (xor-swizzled quads)
__device__ inline void stage_bn(const __hip_bfloat16* __restrict__ src, float* __restrict__ xt,
                                const float* __restrict__ A, const float* __restrict__ Bc,
                                int t, int blockBase)
{
  const uint4* s = (const uint4*)(src + ((size_t)(blockBase + t))*64);
  float* row = &xt[t*64];
  const int sw = t & 7;
#pragma unroll
  for (int g = 0; g < 8; ++g) {
    const uint4 v = s[g];
    const unsigned uu[4] = {v.x, v.y, v.z, v.w};
    const float4 Aq0 = ((const float4*)A)[g*2],  Aq1 = ((const float4*)A)[g*2+1];
    const float4 Bq0 = ((const float4*)Bc)[g*2], Bq1 = ((const float4*)Bc)[g*2+1];
    float e[8];
#pragma unroll
    for (int k = 0; k < 4; ++k) {
      const float f0 = __uint_as_float(uu[k] << 16);
      const float f1 = __uint_as_float(uu[k] & 0xFFFF0000u);
      const float a0 = (k<2) ? ((k==0)?Aq0.x:Aq0.z) : ((k==2)?Aq1.x:Aq1.z);
      const float a1 = (k<2) ? ((k==0)?Aq0.y:Aq0.w) : ((k==2)?Aq1.y:Aq1.w);
      const float bb0 = (k<2) ? ((k==0)?Bq0.x:Bq0.z) : ((k==2)?Bq1.x:Bq1.z);
      const float bb1 = (k<2) ? ((k==0)?Bq0.y:Bq0.w) : ((k==2)?Bq1.y:Bq1.w);
      e[k*2+0] = fmaxf(fmaf(f0, a0, bb0), 0.f);
      e[k*2+1] = fmaxf(fmaf(f1, a1, bb1), 0.f);
    }
    const float4 q0 = make_float4(e[0],e[1],e[2],e[3]);
    const float4 q1 = make_float4(e[4],e[5],e[6],e[7]);
    ((float4*)row)[(g*2)   ^ sw] = q0;
    ((float4*)row)[(g*2+1) ^ sw] = q1;
  }
}

// ---------------------------------------------------------------- K3: bn1+relu -> conv2 -> y2(bf16) + stats2
__global__ __launch_bounds__(256)
void k_l2(const __hip_bfloat16* __restrict__ y1, float* __restrict__ stats,
          const float* __restrict__ g1, const float* __restrict__ be1,
          const float* __restrict__ W2, const float* __restrict__ b2,
          __hip_bfloat16* __restrict__ y2)
{
  __shared__ float xt[256*64];
  __shared__ float A[64], Bc[64], ssh[64], qsh[64];
  const int t = threadIdx.x;
  if (t < 64) {
    const float mean = stats[t*16] * INV_P;
    float var = stats[(64+t)*16] * INV_P - mean*mean;
    if (var < 0.f) var = 0.f;
    const float rs = rsqrtf(var + 1e-5f);
    const float a = rs * g1[t];
    A[t] = a; Bc[t] = fmaf(-mean, a, be1[t]);
    ssh[t] = 0.f; qsh[t] = 0.f;
  }
  const int lane = t & 63, wv = t >> 6;
  float w[64];
#pragma unroll
  for (int c4 = 0; c4 < 16; ++c4) {
    const float4 v = *(const float4*)(W2 + lane*64 + c4*4);
    w[c4*4+0]=v.x; w[c4*4+1]=v.y; w[c4*4+2]=v.z; w[c4*4+3]=v.w;
  }
  const float bo = b2[lane];
  __syncthreads();
  stage_bn(y1, xt, A, Bc, t, blockIdx.x*256);
  __syncthreads();
  float ls = 0.f, lq = 0.f;
  for (int pp = 0; pp < 64; ++pp) {
    const int p = wv*64 + pp;
    const int sw = p & 7;
    const float* row = &xt[p*64];
    float acc = bo;
#pragma unroll
    for (int c4 = 0; c4 < 16; ++c4) {
      const float4 xq = ((const float4*)row)[c4 ^ sw];
      acc = fmaf(w[c4*4+0], xq.x, acc);
      acc = fmaf(w[c4*4+1], xq.y, acc);
      acc = fmaf(w[c4*4+2], xq.z, acc);
      acc = fmaf(w[c4*4+3], xq.w, acc);
    }
    y2[((size_t)(blockIdx.x*256 + p))*64 + lane] = __float2bfloat16(acc);
    ls += acc; lq = fmaf(acc,acc,lq);
  }
  atomicAdd(&ssh[lane], ls);
  atomicAdd(&qsh[lane], lq);
  __syncthreads();
  if (t < 64) {
    atomicAdd(&stats[(128+t)*16], ssh[t]);
    atomicAdd(&stats[(192+t)*16], qsh[t]);
  }
}

// ---------------------------------------------------------------- K4: bn2+relu -> conv3 -> stats3 (no store)
__global__ __launch_bounds__(256)
void k_l3stats(const __hip_bfloat16* __restrict__ y2, float* __restrict__ stats,
               const float* __restrict__ g2, const float* __restrict__ be2,
               const float* __restrict__ W3, const float* __restrict__ b3)
{
  __shared__ float xt[256*64];
  __shared__ float A[64], Bc[64], ssh[128], qsh[128];
  const int t = threadIdx.x;
  if (t < 64) {
    const float mean = stats[(128+t)*16] * INV_P;
    float var = stats[(192+t)*16] * INV_P - mean*mean;
    if (var < 0.f) var = 0.f;
    const float rs = rsqrtf(var + 1e-5f);
    const float a = rs * g2[t];
    A[t] = a; Bc[t] = fmaf(-mean, a, be2[t]);
  }
  if (t < 128) { ssh[t]=0.f; qsh[t]=0.f; }
  const int lane = t & 63, wv = t >> 6;
  float w0[64], w1[64];
#pragma unroll
  for (int c4 = 0; c4 < 16; ++c4) {
    const float4 v  = *(const float4*)(W3 + lane*64 + c4*4);
    const float4 v2 = *(const float4*)(W3 + (size_t)(lane+64)*64 + c4*4);
    w0[c4*4+0]=v.x;  w0[c4*4+1]=v.y;  w0[c4*4+2]=v.z;  w0[c4*4+3]=v.w;
    w1[c4*4+0]=v2.x; w1[c4*4+1]=v2.y; w1[c4*4+2]=v2.z; w1[c4*4+3]=v2.w;
  }
  const float bo0 = b3[lane], bo1 = b3[lane+64];
  __syncthreads();
  stage_bn(y2, xt, A, Bc, t, blockIdx.x*256);
  __syncthreads();
  float ls0=0.f,lq0=0.f,ls1=0.f,lq1=0.f;
  for (int pp = 0; pp < 64; ++pp) {
    const int p = wv*64 + pp;
    const int sw = p & 7;
    const float* row = &xt[p*64];
    float a0 = bo0, a1 = bo1;
#pragma unroll
    for (int c4 = 0; c4 < 16; ++c4) {
      const float4 xq = ((const float4*)row)[c4 ^ sw];
      a0 = fmaf(w0[c4*4+0], xq.x, a0); a0 = fmaf(w0[c4*4+1], xq.y, a0);
      a0 = fmaf(w0[c4*4+2], xq.z, a0); a0 = fmaf(w0[c4*4+3], xq.w, a0);
      a1 = fmaf(w1[c4*4+0], xq.x, a1); a1 = fmaf(w1[c4*4+1], xq.y, a1);
      a1 = fmaf(w1[c4*4+2], xq.z, a1); a1 = fmaf(w1[c4*4+3], xq.w, a1);
    }
    ls0 += a0; lq0 = fmaf(a0,a0,lq0);
    ls1 += a1; lq1 = fmaf(a1,a1,lq1);
  }
  atomicAdd(&ssh[lane], ls0);    atomicAdd(&qsh[lane], lq0);
  atomicAdd(&ssh[64+lane], ls1); atomicAdd(&qsh[64+lane], lq1);
  __syncthreads();
  if (t < 128) {
    atomicAdd(&stats[(256+t)*16], ssh[t]);
    atomicAdd(&stats[(384+t)*16], qsh[t]);
  }
}

// ---------------------------------------------------------------- K5: bn2+relu -> conv3 -> bn3+relu -> max over NSAMPLE -> out
__global__ __launch_bounds__(256)
void k_out(const __hip_bfloat16* __restrict__ y2, const float* __restrict__ stats,
           const float* __restrict__ g2, const float* __restrict__ be2,
           const float* __restrict__ W3, const float* __restrict__ b3,
           const float* __restrict__ g3, const float* __restrict__ be3,
           float* __restrict__ out)
{
  __shared__ float xt[256*64];
  __shared__ float A[64], Bc[64], A3[128], B3[128];
  const int t = threadIdx.x;
  if (t < 64) {
    const float mean = stats[(128+t)*16] * INV_P;
    float var = stats[(192+t)*16] * INV_P - mean*mean;
    if (var < 0.f) var = 0.f;
    const float rs = rsqrtf(var + 1e-5f);
    const float a = rs * g2[t];
    A[t] = a; Bc[t] = fmaf(-mean, a, be2[t]);
  }
  if (t < 128) {
    const float mean = stats[(256+t)*16] * INV_P;
    float var = stats[(384+t)*16] * INV_P - mean*mean;
    if (var < 0.f) var = 0.f;
    const float rs = rsqrtf(var + 1e-5f);
    const float a = rs * g3[t];
    A3[t] = a; B3[t] = fmaf(-mean, a, be3[t]);
  }
  const int lane = t & 63, wv = t >> 6;
  float w0[64], w1[64];
#pragma unroll
  for (int c4 = 0; c4 < 16; ++c4) {
    const float4 v  = *(const float4*)(W3 + lane*64 + c4*4);
    const float4 v2 = *(const float4*)(W3 + (size_t)(lane+64)*64 + c4*4);
    w0[c4*4+0]=v.x;  w0[c4*4+1]=v.y;  w0[c4*4+2]=v.z;  w0[c4*4+3]=v.w;
    w1[c4*4+0]=v2.x; w1[c4*4+1]=v2.y; w1[c4*4+2]=v2.z; w1[c4*4+3]=v2.w;
  }
  const float bo0 = b3[lane], bo1 = b3[lane+64];
  __syncthreads();
  stage_bn(y2, xt, A, Bc, t, blockIdx.x*256);
  __syncthreads();
  const float a3l0 = A3[lane], b3l0 = B3[lane];
  const float a3l1 = A3[64+lane], b3l1 = B3[64+lane];
  for (int which = 0; which < 2; ++which) {
    float mx0 = -1e30f, mx1 = -1e30f;
    for (int j = 0; j < 32; ++j) {
      const int p = (wv*2+which)*32 + j;
      const int sw = p & 7;
      const float* row = &xt[p*64];
      float a0 = bo0, a1 = bo1;
#pragma unroll
      for (int c4 = 0; c4 < 16; ++c4) {
        const float4 xq = ((const float4*)row)[c4 ^ sw];
        a0 = fmaf(w0[c4*4+0], xq.x, a0); a0 = fmaf(w0[c4*4+1], xq.y, a0);
        a0 = fmaf(w0[c4*4+2], xq.z, a0); a0 = fmaf(w0[c4*4+3], xq.w, a0);
        a1 = fmaf(w1[c4*4+0], xq.x, a1); a1 = fmaf(w1[c4*4+1], xq.y, a1);
        a1 = fmaf(w1[c4*4+2], xq.z, a1); a1 = fmaf(w1[c4*4+3], xq.w, a1);
      }
      mx0 = fmaxf(mx0, fmaf(a0, a3l0, b3l0));
      mx1 = fmaxf(mx1, fmaf(a1, a3l1, b3l1));
    }
    const size_t gq = (size_t)blockIdx.x*8 + wv*2 + which;
    out[49152 + gq*128 + lane]      = fmaxf(mx0, 0.f);
    out[49152 + gq*128 + 64 + lane] = fmaxf(mx1, 0.f);
  }
}

// ----------------------------------------------------------------
extern "C" void kernel_launch(void* const* d_in, const int* in_sizes, int n_in,
                              void* d_out, int out_size, void* d_ws, size_t ws_size,
                              hipStream_t stream)
{
  const float* xyz = (const float*)d_in[0];
  const float* pts = (const float*)d_in[1];
  const float* W1  = (const float*)d_in[2];
  const float* b1  = (const float*)d_in[3];
  const float* g1  = (const float*)d_in[4];
  const float* be1 = (const float*)d_in[5];
  const float* W2  = (const float*)d_in[6];
  const float* b2_ = (const float*)d_in[7];
  const float* g2  = (const float*)d_in[8];
  const float* be2 = (const float*)d_in[9];
  const float* W3  = (const float*)d_in[10];
  const float* b3_ = (const float*)d_in[11];
  const float* g3  = (const float*)d_in[12];
  const float* be3 = (const float*)d_in[13];
  float* out = (float*)d_out;
  char* ws = (char*)d_ws;

  float* stats = (float*)(ws);
  float* F     = (float*)(ws + (1u<<20));
  __hip_bfloat16* y1 = (__hip_bfloat16*)(ws + (32u<<20));
  __hip_bfloat16* y2 = (__hip_bfloat16*)(ws + (112u<<20));

  k_fps_pre<<<2056, 128, 0, stream>>>(xyz, pts, W1, b1, F, out, stats);
  k_ball<<<256, 256, 0, stream>>>(xyz, out, F, W1, y1, stats);
  k_l2<<<2048, 256, 0, stream>>>(y1, stats, g1, be1, W2, b2_, y2);
  k_l3stats<<<2048, 256, 0, stream>>>(y2, stats, g2, be2, W3, b3_);
  k_out<<<2048, 256, 0, stream>>>(y2, stats, g2, be2, W3, b3_, g3, be3, out);
}

// Round 14
// 2244.423 us; speedup vs baseline: 1.6737x; 1.6737x over previous
//
#include <hip/hip_runtime.h>
#include <hip/hip_bf16.h>

#define NB 8
#define NN 8192
#define NP 2048
#define NS 32
#define INV_P (1.0f/524288.0f)   // 1/(B*NPOINT*NSAMPLE), exact power of 2

typedef float v2f __attribute__((ext_vector_type(2)));

template<int CTRL>
__device__ __forceinline__ float fmax_dpp(float v) {
  // bound_ctrl=true: invalid-source lanes read 0; distances >= 0 so max(v,0)=v is safe
  const int x = __builtin_amdgcn_update_dpp(0, __float_as_int(v), CTRL, 0xF, 0xF, true);
  return fmaxf(v, __int_as_float(x));
}

// ws layout (bytes):
//  0    : stats, 512 slots x 16 floats = 32KB
//  1MB  : F = W1[:,3:]@feat + b1   (8*8192*64 f32 = 16MB, ends 17MB; dead after K2)
//  17MB : mxbuf (16384 groups x 128 ch f32 = 8MB)
//  25MB : mnbuf (8MB, ends 33MB; overlaps y1's first 1MB -- y1 dead after K3)
//  32MB : y1 bf16 (524288*64) = 67MB
//  112MB: y2 bf16 (524288*64) = 67MB

// ---------------------------------------------------------------- K1: FPS (blocks 0..7, 512 thr — R3-proven config, byte-exact)
//      + F precompute (blocks 8..519)
__global__ __launch_bounds__(512)
void k_fps_pre(const float* __restrict__ xyz, const float* __restrict__ feat,
               const float* __restrict__ W1, const float* __restrict__ b1,
               float* __restrict__ F, float* __restrict__ outXyz, float* __restrict__ stats)
{
#pragma clang fp contract(off)
  __shared__ union U { float4 xyzw[NN]; float fx[128*64]; } sh;
  __shared__ unsigned long long cand[2][8];
  const int t = threadIdx.x;
  if (blockIdx.x < 8) {
    const int b = blockIdx.x;
    const float* xb = xyz + (size_t)b*NN*3;
    v2f px[8], py[8], pz[8], dd[8];
#pragma unroll
    for (int j = 0; j < 8; ++j) {
      const int i0 = t*16 + 2*j;
      const float x0 = xb[i0*3+0], y0 = xb[i0*3+1], z0 = xb[i0*3+2];
      const float x1 = xb[i0*3+3], y1 = xb[i0*3+4], z1 = xb[i0*3+5];
      px[j] = (v2f){x0,x1}; py[j] = (v2f){y0,y1}; pz[j] = (v2f){z0,z1};
      dd[j] = (v2f){1e10f,1e10f};
      sh.xyzw[i0]   = make_float4(x0,y0,z0,0.f);
      sh.xyzw[i0+1] = make_float4(x1,y1,z1,0.f);
    }
    __syncthreads();
    const int lane = t & 63, wv = t >> 6;
    float4 cf = sh.xyzw[0];
    for (int s = 0; s < NP; ++s) {
      if (t == 0) {
        float* o = outXyz + ((size_t)b*NP+s)*3;
        o[0]=cf.x; o[1]=cf.y; o[2]=cf.z;
      }
      const v2f cx = {cf.x,cf.x}, cy = {cf.y,cf.y}, cz = {cf.z,cf.z};
      float m = -1.f; int mi = 0;
#pragma unroll
      for (int j = 0; j < 8; ++j) {
        // EXACT reference rounding: (dx*dx + dy*dy) + dz*dz, no fma (contract off);
        // v_pk_* ops round identically per lane-half
        const v2f dx = px[j]-cx, dy = py[j]-cy, dz = pz[j]-cz;
        v2f d = dx*dx; d = d + dy*dy; d = d + dz*dz;
        const float n0 = fminf(dd[j].x, d.x);   // jnp.minimum
        const float n1 = fminf(dd[j].y, d.y);
        dd[j].x = n0; dd[j].y = n1;
        if (n0 > m) { m = n0; mi = 2*j;   }     // strict > => first occurrence (inline, off the tail path)
        if (n1 > m) { m = n1; mi = 2*j+1; }
      }
      // wave64 value-max via DPP chain -> lane 63 -> SGPR broadcast
      float r = m;
      r = fmax_dpp<0xB1>(r);   // quad_perm [1,0,3,2]
      r = fmax_dpp<0x4E>(r);   // quad_perm [2,3,0,1]
      r = fmax_dpp<0x141>(r);  // row_half_mirror
      r = fmax_dpp<0x140>(r);  // row_mirror
      r = fmax_dpp<0x142>(r);  // row_bcast15
      r = fmax_dpp<0x143>(r);  // row_bcast31
      const int wmb  = __builtin_amdgcn_readlane(__float_as_int(r), 63);
      const float wm = __int_as_float(wmb);
      const unsigned long long mk = __ballot(m == wm);
      const int ls  = __ffsll((long long)mk) - 1;            // first lane achieving wave max
      const int miw = __builtin_amdgcn_readlane(mi, ls);
      const unsigned idx = (unsigned)((wv*64 + ls)*16 + miw);
      if (lane == 0)
        cand[s&1][wv] = ((unsigned long long)(unsigned)wmb << 32)
                      | (unsigned long long)(0xFFFFFFFFu - idx);   // ties -> smaller idx wins
      __syncthreads();
      unsigned long long best = cand[s&1][0];
#pragma unroll
      for (int w = 1; w < 8; ++w) { const unsigned long long c = cand[s&1][w]; if (c > best) best = c; }
      const int far = (int)(0xFFFFFFFFu - (unsigned)(best & 0xFFFFFFFFull));
      cf = sh.xyzw[far];
    }
  } else {
    if (blockIdx.x == 8) {             // zero the stats table once per launch
      for (int i = t; i < 512*16; i += 512) stats[i] = 0.f;
    }
    const int blk = blockIdx.x - 8;    // 0..511, 128 point-rows each
    const int base = blk * 128;
    const int b = base >> 13;
    const int n0 = base & (NN-1);
    {
      const int row = t >> 2, seg = t & 3;
      const float* src = feat + ((size_t)(b*NN + n0 + row))*64 + seg*16;
#pragma unroll
      for (int k = 0; k < 4; ++k) {
        const float4 v = *(const float4*)(src + k*4);
        *(float4*)&sh.fx[row*64 + seg*16 + k*4] = v;
      }
    }
    __syncthreads();
    const int o = t & 63, wv = t >> 6;
    float w[64];
#pragma unroll
    for (int c = 0; c < 64; ++c) w[c] = W1[o*67 + 3 + c];
    const float bb = b1[o];
    for (int r = wv*16; r < wv*16+16; ++r) {
      float acc = bb;
#pragma unroll
      for (int c4 = 0; c4 < 16; ++c4) {
        const float4 xq = *(const float4*)&sh.fx[r*64 + c4*4];
        acc = fmaf(w[c4*4+0], xq.x, acc);
        acc = fmaf(w[c4*4+1], xq.y, acc);
        acc = fmaf(w[c4*4+2], xq.z, acc);
        acc = fmaf(w[c4*4+3], xq.w, acc);
      }
      F[((size_t)(b*NN + n0 + r))*64 + o] = acc;
    }
  }
}

// ---------------------------------------------------------------- K2: ball query (f64 exact-geometry membership) + gather + conv1 -> y1(bf16) + stats1
__global__ __launch_bounds__(256)
void k_ball(const float* __restrict__ xyz, const float* __restrict__ newXyz,
            const float* __restrict__ F, const float* __restrict__ W1,
            __hip_bfloat16* __restrict__ y1, float* __restrict__ stats)
{
  __shared__ float xs[NN], ys[NN], zs[NN];
  __shared__ int sel[4][NS];
  const int t = threadIdx.x;
  const int b = blockIdx.x >> 5;
  const int chunk = blockIdx.x & 31;
  const float* xb = xyz + (size_t)b*NN*3;
  for (int i = t; i < NN; i += 256) {
    xs[i] = xb[i*3+0]; ys[i] = xb[i*3+1]; zs[i] = xb[i*3+2];
  }
  __syncthreads();
  const int lane = t & 63, wv = t >> 6;
  const float w0 = W1[lane*67+0], w1 = W1[lane*67+1], w2 = W1[lane*67+2];
  const double rr = 0.2*0.2;   // exact Python double radius*radius
  float ls = 0.f, lq = 0.f;
  for (int qi = 0; qi < 16; ++qi) {
    const int q  = chunk*64 + wv*16 + qi;
    const int gq = b*NP + q;
    const float cx = newXyz[(size_t)gq*3+0], cy = newXyz[(size_t)gq*3+1], cz = newXyz[(size_t)gq*3+2];
    const double cxd = (double)cx, cyd = (double)cy, czd = (double)cz;
    const double ssd = cxd*cxd + cyd*cyd + czd*czd;
    int have = 0;
    for (int c0 = 0; c0 < NN; c0 += 64) {
      const int i = c0 + lane;
      // true squared distance in f64 (inputs are exact f32): robust to every
      // f32 ordering the reference might have used (min boundary gap ~2e-7 >> 1e-16)
      const double x = (double)xs[i], y = (double)ys[i], z = (double)zs[i];
      const double dot = x*cxd + y*cyd + z*czd;
      const double pn2 = x*x + y*y + z*z;
      const double d = -2.0*dot + ssd + pn2;
      const bool ok = d <= rr;
      const unsigned long long mk = __ballot(ok);
      const int rank = __popcll(mk & ((1ull<<lane)-1ull));
      if (ok && have + rank < NS) sel[wv][have+rank] = i;
      have += (int)__popcll(mk);
      if (have >= NS) break;
    }
    if (have > NS) have = NS;
    const int first = sel[wv][0];
    if (lane >= have && lane < NS) sel[wv][lane] = first;  // pad tail with first index
    for (int j = 0; j < NS; ++j) {
      const int i = sel[wv][j];
      const float dxn = xs[i]-cx, dyn = ys[i]-cy, dzn = zs[i]-cz;
      const float f = F[((size_t)(b*NN+i))*64 + lane];
      float yv = fmaf(w0,dxn,f); yv = fmaf(w1,dyn,yv); yv = fmaf(w2,dzn,yv);
      y1[((size_t)gq*NS + j)*64 + lane] = __float2bfloat16(yv);
      ls += yv; lq = fmaf(yv,yv,lq);
    }
  }
  atomicAdd(&stats[(0 +lane)*16], ls);
  atomicAdd(&stats[(64+lane)*16], lq);
}

// ---------------------------------------------------------------- staging helper: bf16 tile -> bn+relu -> LDS (xor-swizzled quads)
__device__ inline void stage_bn(const __hip_bfloat16* __restrict__ src, float* __restrict__ xt,
                                const float* __restrict__ A, const float* __restrict__ Bc,
                                int t, int blockBase)
{
  const uint4* s = (const uint4*)(src + ((size_t)(blockBase + t))*64);
  float* row = &xt[t*64];
  const int sw = t & 7;
#pragma unroll
  for (int g = 0; g < 8; ++g) {
    const uint4 v = s[g];
    const unsigned uu[4] = {v.x, v.y, v.z, v.w};
    const float4 Aq0 = ((const float4*)A)[g*2],  Aq1 = ((const float4*)A)[g*2+1];
    const float4 Bq0 = ((const float4*)Bc)[g*2], Bq1 = ((const float4*)Bc)[g*2+1];
    float e[8];
#pragma unroll
    for (int k = 0; k < 4; ++k) {
      const float f0 = __uint_as_float(uu[k] << 16);
      const float f1 = __uint_as_float(uu[k] & 0xFFFF0000u);
      const float a0 = (k<2) ? ((k==0)?Aq0.x:Aq0.z) : ((k==2)?Aq1.x:Aq1.z);
      const float a1 = (k<2) ? ((k==0)?Aq0.y:Aq0.w) : ((k==2)?Aq1.y:Aq1.w);
      const float bb0 = (k<2) ? ((k==0)?Bq0.x:Bq0.z) : ((k==2)?Bq1.x:Bq1.z);
      const float bb1 = (k<2) ? ((k==0)?Bq0.y:Bq0.w) : ((k==2)?Bq1.y:Bq1.w);
      e[k*2+0] = fmaxf(fmaf(f0, a0, bb0), 0.f);
      e[k*2+1] = fmaxf(fmaf(f1, a1, bb1), 0.f);
    }
    const float4 q0 = make_float4(e[0],e[1],e[2],e[3]);
    const float4 q1 = make_float4(e[4],e[5],e[6],e[7]);
    ((float4*)row)[(g*2)   ^ sw] = q0;
    ((float4*)row)[(g*2+1) ^ sw] = q1;
  }
}

// ---------------------------------------------------------------- K3: bn1+relu -> conv2 -> y2(bf16) + stats2
__global__ __launch_bounds__(256)
void k_l2(const __hip_bfloat16* __restrict__ y1, float* __restrict__ stats,
          const float* __restrict__ g1, const float* __restrict__ be1,
          const float* __restrict__ W2, const float* __restrict__ b2,
          __hip_bfloat16* __restrict__ y2)
{
  __shared__ float xt[256*64];
  __shared__ float A[64], Bc[64], ssh[64], qsh[64];
  const int t = threadIdx.x;
  if (t < 64) {
    const float mean = stats[t*16] * INV_P;
    float var = stats[(64+t)*16] * INV_P - mean*mean;
    if (var < 0.f) var = 0.f;
    const float rs = rsqrtf(var + 1e-5f);
    const float a = rs * g1[t];
    A[t] = a; Bc[t] = fmaf(-mean, a, be1[t]);
    ssh[t] = 0.f; qsh[t] = 0.f;
  }
  const int lane = t & 63, wv = t >> 6;
  float w[64];
#pragma unroll
  for (int c4 = 0; c4 < 16; ++c4) {
    const float4 v = *(const float4*)(W2 + lane*64 + c4*4);
    w[c4*4+0]=v.x; w[c4*4+1]=v.y; w[c4*4+2]=v.z; w[c4*4+3]=v.w;
  }
  const float bo = b2[lane];
  __syncthreads();
  stage_bn(y1, xt, A, Bc, t, blockIdx.x*256);
  __syncthreads();
  float ls = 0.f, lq = 0.f;
  for (int pp = 0; pp < 64; ++pp) {
    const int p = wv*64 + pp;
    const int sw = p & 7;
    const float* row = &xt[p*64];
    float acc = bo;
#pragma unroll
    for (int c4 = 0; c4 < 16; ++c4) {
      const float4 xq = ((const float4*)row)[c4 ^ sw];
      acc = fmaf(w[c4*4+0], xq.x, acc);
      acc = fmaf(w[c4*4+1], xq.y, acc);
      acc = fmaf(w[c4*4+2], xq.z, acc);
      acc = fmaf(w[c4*4+3], xq.w, acc);
    }
    y2[((size_t)(blockIdx.x*256 + p))*64 + lane] = __float2bfloat16(acc);
    ls += acc; lq = fmaf(acc,acc,lq);
  }
  atomicAdd(&ssh[lane], ls);
  atomicAdd(&qsh[lane], lq);
  __syncthreads();
  if (t < 64) {
    atomicAdd(&stats[(128+t)*16], ssh[t]);
    atomicAdd(&stats[(192+t)*16], qsh[t]);
  }
}

// ---------------------------------------------------------------- K4': bn2+relu -> conv3 -> stats3 + per-(group32,ch) f32 min/max
__global__ __launch_bounds__(256)
void k_l3(const __hip_bfloat16* __restrict__ y2, float* __restrict__ stats,
          const float* __restrict__ g2, const float* __restrict__ be2,
          const float* __restrict__ W3, const float* __restrict__ b3,
          float* __restrict__ mxbuf, float* __restrict__ mnbuf)
{
  __shared__ float xt[256*64];
  __shared__ float A[64], Bc[64], ssh[128], qsh[128];
  const int t = threadIdx.x;
  if (t < 64) {
    const float mean = stats[(128+t)*16] * INV_P;
    float var = stats[(192+t)*16] * INV_P - mean*mean;
    if (var < 0.f) var = 0.f;
    const float rs = rsqrtf(var + 1e-5f);
    const float a = rs * g2[t];
    A[t] = a; Bc[t] = fmaf(-mean, a, be2[t]);
  }
  if (t < 128) { ssh[t]=0.f; qsh[t]=0.f; }
  const int lane = t & 63, wv = t >> 6;
  float w0[64], w1[64];
#pragma unroll
  for (int c4 = 0; c4 < 16; ++c4) {
    const float4 v  = *(const float4*)(W3 + lane*64 + c4*4);
    const float4 v2 = *(const float4*)(W3 + (size_t)(lane+64)*64 + c4*4);
    w0[c4*4+0]=v.x;  w0[c4*4+1]=v.y;  w0[c4*4+2]=v.z;  w0[c4*4+3]=v.w;
    w1[c4*4+0]=v2.x; w1[c4*4+1]=v2.y; w1[c4*4+2]=v2.z; w1[c4*4+3]=v2.w;
  }
  const float bo0 = b3[lane], bo1 = b3[lane+64];
  __syncthreads();
  stage_bn(y2, xt, A, Bc, t, blockIdx.x*256);
  __syncthreads();
  float ls0=0.f,lq0=0.f,ls1=0.f,lq1=0.f;
  for (int which = 0; which < 2; ++which) {
    float mx0 = -1e30f, mx1 = -1e30f, mn0 = 1e30f, mn1 = 1e30f;
    for (int j = 0; j < 32; ++j) {
      const int p = (wv*2+which)*32 + j;
      const int sw = p & 7;
      const float* row = &xt[p*64];
      float a0 = bo0, a1 = bo1;
#pragma unroll
      for (int c4 = 0; c4 < 16; ++c4) {
        const float4 xq = ((const float4*)row)[c4 ^ sw];
        a0 = fmaf(w0[c4*4+0], xq.x, a0); a0 = fmaf(w0[c4*4+1], xq.y, a0);
        a0 = fmaf(w0[c4*4+2], xq.z, a0); a0 = fmaf(w0[c4*4+3], xq.w, a0);
        a1 = fmaf(w1[c4*4+0], xq.x, a1); a1 = fmaf(w1[c4*4+1], xq.y, a1);
        a1 = fmaf(w1[c4*4+2], xq.z, a1); a1 = fmaf(w1[c4*4+3], xq.w, a1);
      }
      ls0 += a0; lq0 = fmaf(a0,a0,lq0);
      ls1 += a1; lq1 = fmaf(a1,a1,lq1);
      mx0 = fmaxf(mx0, a0); mn0 = fminf(mn0, a0);
      mx1 = fmaxf(mx1, a1); mn1 = fminf(mn1, a1);
    }
    const size_t gq = (size_t)blockIdx.x*8 + wv*2 + which;
    mxbuf[gq*128 + lane]      = mx0;  mnbuf[gq*128 + lane]      = mn0;
    mxbuf[gq*128 + 64 + lane] = mx1;  mnbuf[gq*128 + 64 + lane] = mn1;
  }
  atomicAdd(&ssh[lane], ls0);    atomicAdd(&qsh[lane], lq0);
  atomicAdd(&ssh[64+lane], ls1); atomicAdd(&qsh[64+lane], lq1);
  __syncthreads();
  if (t < 128) {
    atomicAdd(&stats[(256+t)*16], ssh[t]);
    atomicAdd(&stats[(384+t)*16], qsh[t]);
  }
}

// ---------------------------------------------------------------- K5': bn3 via sign-select on min/max + relu -> out (tiny)
__global__ __launch_bounds__(256)
void k_out2(const float* __restrict__ mxbuf, const float* __restrict__ mnbuf,
            const float* __restrict__ stats, const float* __restrict__ g3,
            const float* __restrict__ be3, float* __restrict__ out)
{
  const int idx = blockIdx.x*256 + threadIdx.x;   // 0 .. 16384*128-1
  const int ch = idx & 127;
  const float mean = stats[(256+ch)*16] * INV_P;
  float var = stats[(384+ch)*16] * INV_P - mean*mean;
  if (var < 0.f) var = 0.f;
  const float rs = rsqrtf(var + 1e-5f);
  const float a = rs * g3[ch];
  const float bc = fmaf(-mean, a, be3[ch]);
  // max_j relu(a*x_j + bc) = relu(fmaf(a, a>=0 ? max_j x_j : min_j x_j, bc))  (fmaf monotone in x)
  const float x = (a >= 0.f) ? mxbuf[idx] : mnbuf[idx];
  out[49152 + idx] = fmaxf(fmaf(a, x, bc), 0.f);
}

// ----------------------------------------------------------------
extern "C" void kernel_launch(void* const* d_in, const int* in_sizes, int n_in,
                              void* d_out, int out_size, void* d_ws, size_t ws_size,
                              hipStream_t stream)
{
  const float* xyz = (const float*)d_in[0];
  const float* pts = (const float*)d_in[1];
  const float* W1  = (const float*)d_in[2];
  const float* b1  = (const float*)d_in[3];
  const float* g1  = (const float*)d_in[4];
  const float* be1 = (const float*)d_in[5];
  const float* W2  = (const float*)d_in[6];
  const float* b2_ = (const float*)d_in[7];
  const float* g2  = (const float*)d_in[8];
  const float* be2 = (const float*)d_in[9];
  const float* W3  = (const float*)d_in[10];
  const float* b3_ = (const float*)d_in[11];
  const float* g3  = (const float*)d_in[12];
  const float* be3 = (const float*)d_in[13];
  float* out = (float*)d_out;
  char* ws = (char*)d_ws;

  float* stats = (float*)(ws);
  float* F     = (float*)(ws + (1u<<20));
  float* mxbuf = (float*)(ws + (17u<<20));
  float* mnbuf = (float*)(ws + (25u<<20));
  __hip_bfloat16* y1 = (__hip_bfloat16*)(ws + (32u<<20));
  __hip_bfloat16* y2 = (__hip_bfloat16*)(ws + (112u<<20));

  k_fps_pre<<<520, 512, 0, stream>>>(xyz, pts, W1, b1, F, out, stats);
  k_ball<<<256, 256, 0, stream>>>(xyz, out, F, W1, y1, stats);
  k_l2<<<2048, 256, 0, stream>>>(y1, stats, g1, be1, W2, b2_, y2);
  k_l3<<<2048, 256, 0, stream>>>(y2, stats, g2, be2, W3, b3_, mxbuf, mnbuf);
  k_out2<<<8192, 256, 0, stream>>>(mxbuf, mnbuf, stats, g3, be3, out);
}